// Round 1
// baseline (497.918 us; speedup 1.0000x reference)
//
#include <hip/hip_runtime.h>
#include <hip/hip_bf16.h>

#define SEQ_L 2048
#define NBATCH 4
#define EDIM 1024
#define NHEAD 16
#define DHEAD 64

typedef __attribute__((ext_vector_type(4))) float f32x4;
typedef __attribute__((ext_vector_type(8))) short short8;
typedef unsigned short u16;

__device__ __forceinline__ u16 f2bf(float f){
  unsigned u = __float_as_uint(f);
  u += 0x7fffu + ((u >> 16) & 1u);   // round-to-nearest-even
  return (u16)(u >> 16);
}

// ---------------- fp32 -> bf16 convert ----------------
__global__ __launch_bounds__(256) void cvt_f32_bf16(const float* __restrict__ src,
                                                    u16* __restrict__ dst, int n4){
  int i = blockIdx.x * 256 + threadIdx.x;
  if (i < n4){
    float4 v = reinterpret_cast<const float4*>(src)[i];
    ushort4 o;
    o.x = f2bf(v.x); o.y = f2bf(v.y); o.z = f2bf(v.z); o.w = f2bf(v.w);
    reinterpret_cast<ushort4*>(dst)[i] = o;
  }
}

// ---------------- QKV projection GEMM ----------------
// C[i,f] = sum_e X[i,e] * W[f,e];  i = l*4+n (8192), f = which*1024 + h*64 + d (3072)
// scatter-stores into Q/K/V laid out [N][H][L][DH] bf16; Q scaled by 0.125 (exact).
__global__ __launch_bounds__(256) void qkv_gemm(const u16* __restrict__ X,
                                                const u16* __restrict__ W,
                                                u16* __restrict__ Qd,
                                                u16* __restrict__ Kd,
                                                u16* __restrict__ Vd){
  __shared__ u16 XL[128*72];   // 128 rows x BK=64, stride 72 (pad 16B -> ~2-way banks)
  __shared__ u16 WL[128*72];
  const int tid = threadIdx.x;
  const int lane = tid & 63;
  const int wid = tid >> 6;
  const int wr = wid >> 1, wc = wid & 1;
  const int lr = lane & 15, lg = lane >> 4;
  const int bm = blockIdx.x, bn = blockIdx.y;
  f32x4 acc[4][4] = {};
  for (int kt = 0; kt < 16; ++kt){
    __syncthreads();
#pragma unroll
    for (int it = 0; it < 4; ++it){
      int c = tid + 256*it;
      int row = c >> 3, c8 = (c & 7) * 8;
      *(short8*)&XL[row*72 + c8] = *(const short8*)&X[(bm*128 + row)*EDIM + kt*64 + c8];
      *(short8*)&WL[row*72 + c8] = *(const short8*)&W[(bn*128 + row)*EDIM + kt*64 + c8];
    }
    __syncthreads();
#pragma unroll
    for (int ks = 0; ks < 2; ++ks){
      short8 a[4], b[4];
#pragma unroll
      for (int m = 0; m < 4; ++m)  a[m]  = *(short8*)&XL[(wr*64 + m*16  + lr)*72 + ks*32 + lg*8];
#pragma unroll
      for (int nn = 0; nn < 4; ++nn) b[nn] = *(short8*)&WL[(wc*64 + nn*16 + lr)*72 + ks*32 + lg*8];
#pragma unroll
      for (int m = 0; m < 4; ++m)
#pragma unroll
        for (int nn = 0; nn < 4; ++nn)
          acc[m][nn] = __builtin_amdgcn_mfma_f32_16x16x32_bf16(a[m], b[nn], acc[m][nn], 0, 0, 0);
    }
  }
#pragma unroll
  for (int m = 0; m < 4; ++m){
    const int i0 = bm*128 + wr*64 + m*16 + lg*4;
#pragma unroll
    for (int nn = 0; nn < 4; ++nn){
      const int f = bn*128 + wc*64 + nn*16 + lr;
      const int which = f >> 10;
      const int h = (f >> 6) & 15;
      const int d = f & 63;
      u16* dst = (which == 0) ? Qd : ((which == 1) ? Kd : Vd);
      const float sc = (which == 0) ? 0.125f : 1.0f;   // fold DH^-0.5 into Q (exact pow2)
#pragma unroll
      for (int r = 0; r < 4; ++r){
        const int i = i0 + r;
        const int l = i >> 2, n = i & 3;
        dst[((n*NHEAD + h)*SEQ_L + l)*DHEAD + d] = f2bf(acc[m][nn][r] * sc);
      }
    }
  }
}

// ---------------- flash attention per (n,h) ----------------
// Block = 4 waves, each wave owns 16 q-rows; loop over 2048 keys in 32-key tiles.
// S natural orientation: D[q][key], row q = lg*4+r, col key = lr. Online softmax
// reduces over the 16 lanes of each lane-group. P transposed through wave-private LDS.
__global__ __launch_bounds__(256) void attn(const u16* __restrict__ Qd,
                                            const u16* __restrict__ Kd,
                                            const u16* __restrict__ Vd,
                                            u16* __restrict__ Ctx){
  __shared__ u16 KL[32*72];    // K tile [32 keys][64 d], stride 72
  __shared__ u16 VtL[64*40];   // V^T tile [64 d][32 keys], stride 40
  __shared__ u16 PL[4*16*40];  // per-wave P [16 q][32 keys], stride 40
  const int tid = threadIdx.x;
  const int lane = tid & 63;
  const int wid = tid >> 6;
  const int lr = lane & 15, lg = lane >> 4;
  const int head = blockIdx.y;            // n*16 + h
  const int n = head >> 4, h = head & 15;
  const u16* qh = Qd + head * (SEQ_L * DHEAD);
  const u16* kh = Kd + head * (SEQ_L * DHEAD);
  const u16* vh = Vd + head * (SEQ_L * DHEAD);
  const int q0 = blockIdx.x * 64 + wid * 16;
  short8 aq[2];
#pragma unroll
  for (int ks = 0; ks < 2; ++ks)
    aq[ks] = *(const short8*)&qh[(q0 + lr)*DHEAD + ks*32 + lg*8];
  f32x4 acc[4] = {};
  float mrun[4], lrun[4];
#pragma unroll
  for (int r = 0; r < 4; ++r){ mrun[r] = -1e30f; lrun[r] = 0.0f; }
  u16* myP = &PL[wid * 16 * 40];

  for (int kb0 = 0; kb0 < SEQ_L; kb0 += 32){
    __syncthreads();
    { // stage K tile (row-major) and V tile (transposed)
      const int row = tid >> 3, c8 = (tid & 7) * 8;
      *(short8*)&KL[row*72 + c8] = *(const short8*)&kh[(kb0 + row)*DHEAD + c8];
      short8 vv = *(const short8*)&vh[(kb0 + row)*DHEAD + c8];
#pragma unroll
      for (int j = 0; j < 8; ++j)
        VtL[(c8 + j)*40 + row] = (u16)vv[j];
    }
    __syncthreads();
    // S = Q K^T for 32 keys (scale already folded into Q)
    f32x4 s[2];
#pragma unroll
    for (int kb = 0; kb < 2; ++kb){
      short8 b0 = *(short8*)&KL[(kb*16 + lr)*72 + lg*8];
      short8 b1 = *(short8*)&KL[(kb*16 + lr)*72 + 32 + lg*8];
      f32x4 z = {0.f, 0.f, 0.f, 0.f};
      z = __builtin_amdgcn_mfma_f32_16x16x32_bf16(aq[0], b0, z, 0, 0, 0);
      z = __builtin_amdgcn_mfma_f32_16x16x32_bf16(aq[1], b1, z, 0, 0, 0);
      s[kb] = z;
    }
    // online softmax per q-row (row = lg*4 + r); reduce across 16 lanes in group
    float alpha[4];
#pragma unroll
    for (int r = 0; r < 4; ++r){
      float mx = fmaxf(s[0][r], s[1][r]);
#pragma unroll
      for (int mm = 1; mm < 16; mm <<= 1) mx = fmaxf(mx, __shfl_xor(mx, mm));
      const float mnew = fmaxf(mrun[r], mx);
      alpha[r] = __expf(mrun[r] - mnew);
      const float p0 = __expf(s[0][r] - mnew);
      const float p1 = __expf(s[1][r] - mnew);
      s[0][r] = p0; s[1][r] = p1;
      float ps = p0 + p1;
#pragma unroll
      for (int mm = 1; mm < 16; mm <<= 1) ps += __shfl_xor(ps, mm);
      lrun[r] = lrun[r]*alpha[r] + ps;
      mrun[r] = mnew;
    }
#pragma unroll
    for (int db = 0; db < 4; ++db)
#pragma unroll
      for (int r = 0; r < 4; ++r) acc[db][r] *= alpha[r];
    // P -> LDS (bf16), transpose to A-fragment layout
#pragma unroll
    for (int kb = 0; kb < 2; ++kb)
#pragma unroll
      for (int r = 0; r < 4; ++r)
        myP[(lg*4 + r)*40 + kb*16 + lr] = f2bf(s[kb][r]);
    asm volatile("s_waitcnt lgkmcnt(0)" ::: "memory");  // cross-lane LDS RAW within wave
    short8 ap = *(short8*)&myP[lr*40 + lg*8];
#pragma unroll
    for (int db = 0; db < 4; ++db){
      short8 bv = *(short8*)&VtL[(db*16 + lr)*40 + lg*8];
      acc[db] = __builtin_amdgcn_mfma_f32_16x16x32_bf16(ap, bv, acc[db], 0, 0, 0);
    }
  }
  // epilogue: ctx[l, n, h*64+d] bf16, normalized by row sum
#pragma unroll
  for (int r = 0; r < 4; ++r){
    const float inv = 1.0f / lrun[r];
    const int ql = q0 + lg*4 + r;
#pragma unroll
    for (int db = 0; db < 4; ++db)
      Ctx[(ql*NBATCH + n)*EDIM + h*DHEAD + db*16 + lr] = f2bf(acc[db][r] * inv);
  }
}

// ---------------- output projection GEMM ----------------
__global__ __launch_bounds__(256) void out_gemm(const u16* __restrict__ X,
                                                const u16* __restrict__ W,
                                                float* __restrict__ O){
  __shared__ u16 XL[128*72];
  __shared__ u16 WL[128*72];
  const int tid = threadIdx.x;
  const int lane = tid & 63;
  const int wid = tid >> 6;
  const int wr = wid >> 1, wc = wid & 1;
  const int lr = lane & 15, lg = lane >> 4;
  const int bm = blockIdx.x, bn = blockIdx.y;
  f32x4 acc[4][4] = {};
  for (int kt = 0; kt < 16; ++kt){
    __syncthreads();
#pragma unroll
    for (int it = 0; it < 4; ++it){
      int c = tid + 256*it;
      int row = c >> 3, c8 = (c & 7) * 8;
      *(short8*)&XL[row*72 + c8] = *(const short8*)&X[(bm*128 + row)*EDIM + kt*64 + c8];
      *(short8*)&WL[row*72 + c8] = *(const short8*)&W[(bn*128 + row)*EDIM + kt*64 + c8];
    }
    __syncthreads();
#pragma unroll
    for (int ks = 0; ks < 2; ++ks){
      short8 a[4], b[4];
#pragma unroll
      for (int m = 0; m < 4; ++m)  a[m]  = *(short8*)&XL[(wr*64 + m*16  + lr)*72 + ks*32 + lg*8];
#pragma unroll
      for (int nn = 0; nn < 4; ++nn) b[nn] = *(short8*)&WL[(wc*64 + nn*16 + lr)*72 + ks*32 + lg*8];
#pragma unroll
      for (int m = 0; m < 4; ++m)
#pragma unroll
        for (int nn = 0; nn < 4; ++nn)
          acc[m][nn] = __builtin_amdgcn_mfma_f32_16x16x32_bf16(a[m], b[nn], acc[m][nn], 0, 0, 0);
    }
  }
#pragma unroll
  for (int m = 0; m < 4; ++m){
    const int i0 = bm*128 + wr*64 + m*16 + lg*4;
#pragma unroll
    for (int nn = 0; nn < 4; ++nn){
      const int f = bn*128 + wc*64 + nn*16 + lr;
#pragma unroll
      for (int r = 0; r < 4; ++r)
        O[(size_t)(i0 + r)*EDIM + f] = acc[m][nn][r];
    }
  }
}

extern "C" void kernel_launch(void* const* d_in, const int* in_sizes, int n_in,
                              void* d_out, int out_size, void* d_ws, size_t ws_size,
                              hipStream_t stream){
  const float* x    = (const float*)d_in[0];
  const float* wqkv = (const float*)d_in[1];
  const float* wout = (const float*)d_in[2];
  float* out = (float*)d_out;
  u16* ws = (u16*)d_ws;
  const size_t XN  = (size_t)SEQ_L * NBATCH * EDIM; // 8388608
  const size_t WQN = (size_t)3 * EDIM * EDIM;       // 3145728
  const size_t WON = (size_t)EDIM * EDIM;           // 1048576
  u16* xb    = ws;               // bf16 x  [8192][1024]
  u16* wqkvb = xb + XN;          // bf16 Wqkv [3072][1024]
  u16* woutb = wqkvb + WQN;      // bf16 Wout [1024][1024]
  u16* qd    = woutb + WON;      // [N][H][L][DH]
  u16* kd    = qd + XN;
  u16* vd    = kd + XN;
  u16* ctx   = xb;               // reuse xb region after qkv_gemm consumed it
  // total ws use: 37,748,736 u16 = 75.5 MB

  cvt_f32_bf16<<<(int)(XN  / 1024), 256, 0, stream>>>(x,    xb,    (int)(XN  / 4));
  cvt_f32_bf16<<<(int)(WQN / 1024), 256, 0, stream>>>(wqkv, wqkvb, (int)(WQN / 4));
  cvt_f32_bf16<<<(int)(WON / 1024), 256, 0, stream>>>(wout, woutb, (int)(WON / 4));
  qkv_gemm<<<dim3(64, 24), 256, 0, stream>>>(xb, wqkvb, qd, kd, vd);
  attn    <<<dim3(32, 64), 256, 0, stream>>>(qd, kd, vd, ctx);
  out_gemm<<<dim3(64, 8),  256, 0, stream>>>(ctx, woutb, out);
}

// Round 2
// 342.442 us; speedup vs baseline: 1.4540x; 1.4540x over previous
//
#include <hip/hip_runtime.h>
#include <hip/hip_bf16.h>

#define SEQ_L 2048
#define NBATCH 4
#define EDIM 1024
#define NHEAD 16
#define DHEAD 64

typedef __attribute__((ext_vector_type(4))) float f32x4;
typedef __attribute__((ext_vector_type(8))) short short8;
typedef unsigned short u16;

__device__ __forceinline__ u16 f2bf(float f){
  unsigned u = __float_as_uint(f);
  u += 0x7fffu + ((u >> 16) & 1u);   // round-to-nearest-even
  return (u16)(u >> 16);
}

// ---------------- fp32 -> bf16 convert ----------------
__global__ __launch_bounds__(256) void cvt_f32_bf16(const float* __restrict__ src,
                                                    u16* __restrict__ dst, int n4){
  int i = blockIdx.x * 256 + threadIdx.x;
  if (i < n4){
    float4 v = reinterpret_cast<const float4*>(src)[i];
    ushort4 o;
    o.x = f2bf(v.x); o.y = f2bf(v.y); o.z = f2bf(v.z); o.w = f2bf(v.w);
    reinterpret_cast<ushort4*>(dst)[i] = o;
  }
}

// ---------------- QKV projection GEMM ----------------
// C[i,f] = sum_e X[i,e] * W[f,e];  i = l*4+n (8192), f = which*1024 + h*64 + d (3072)
// Q scaled by 0.125 (exact pow2). V stored TRANSPOSED: [N][H][DH][L] so the
// attention kernel needs no LDS transpose (the round-1 bank-conflict source).
__global__ __launch_bounds__(256) void qkv_gemm(const u16* __restrict__ X,
                                                const u16* __restrict__ W,
                                                u16* __restrict__ Qd,
                                                u16* __restrict__ Kd,
                                                u16* __restrict__ Vt){
  __shared__ u16 XL[128*72];
  __shared__ u16 WL[128*72];
  const int tid = threadIdx.x;
  const int lane = tid & 63;
  const int wid = tid >> 6;
  const int wr = wid >> 1, wc = wid & 1;
  const int lr = lane & 15, lg = lane >> 4;
  const int bm = blockIdx.x, bn = blockIdx.y;
  f32x4 acc[4][4] = {};
  for (int kt = 0; kt < 16; ++kt){
    __syncthreads();
#pragma unroll
    for (int it = 0; it < 4; ++it){
      int c = tid + 256*it;
      int row = c >> 3, c8 = (c & 7) * 8;
      *(short8*)&XL[row*72 + c8] = *(const short8*)&X[(bm*128 + row)*EDIM + kt*64 + c8];
      *(short8*)&WL[row*72 + c8] = *(const short8*)&W[(bn*128 + row)*EDIM + kt*64 + c8];
    }
    __syncthreads();
#pragma unroll
    for (int ks = 0; ks < 2; ++ks){
      short8 a[4], b[4];
#pragma unroll
      for (int m = 0; m < 4; ++m)  a[m]  = *(short8*)&XL[(wr*64 + m*16  + lr)*72 + ks*32 + lg*8];
#pragma unroll
      for (int nn = 0; nn < 4; ++nn) b[nn] = *(short8*)&WL[(wc*64 + nn*16 + lr)*72 + ks*32 + lg*8];
#pragma unroll
      for (int m = 0; m < 4; ++m)
#pragma unroll
        for (int nn = 0; nn < 4; ++nn)
          acc[m][nn] = __builtin_amdgcn_mfma_f32_16x16x32_bf16(a[m], b[nn], acc[m][nn], 0, 0, 0);
    }
  }
#pragma unroll
  for (int m = 0; m < 4; ++m){
    const int i0 = bm*128 + wr*64 + m*16 + lg*4;
    const int l = i0 >> 2;           // i0 % 4 == 0: the 4 r's are the 4 batches at row l
#pragma unroll
    for (int nn = 0; nn < 4; ++nn){
      const int f = bn*128 + wc*64 + nn*16 + lr;
      const int which = f >> 10;
      const int h = (f >> 6) & 15;
      const int d = f & 63;
#pragma unroll
      for (int r = 0; r < 4; ++r){
        const int n = r;
        if (which == 0)
          Qd[((n*NHEAD + h)*SEQ_L + l)*DHEAD + d] = f2bf(acc[m][nn][r] * 0.125f);
        else if (which == 1)
          Kd[((n*NHEAD + h)*SEQ_L + l)*DHEAD + d] = f2bf(acc[m][nn][r]);
        else
          Vt[((size_t)(n*NHEAD + h)*DHEAD + d)*SEQ_L + l] = f2bf(acc[m][nn][r]);
      }
    }
  }
}

// ---------------- flash attention per (n,h) ----------------
// Block = 4 waves, each wave owns 16 q-rows; 64-key tiles (32 iterations).
// K tile [64 keys][64 d] and V^T tile [64 d][64 keys] staged with vectorized
// loads, stride 72 (conflict-free for the b128 read pattern). P goes through
// per-wave LDS with XOR swizzle col ^= (row>>2)<<4 (lg-groups -> disjoint banks).
__global__ __launch_bounds__(256) void attn(const u16* __restrict__ Qd,
                                            const u16* __restrict__ Kd,
                                            const u16* __restrict__ Vt,
                                            u16* __restrict__ Ctx){
  __shared__ u16 KL[64*72];
  __shared__ u16 VtL[64*72];
  __shared__ u16 PL[4*16*72];
  const int tid = threadIdx.x;
  const int lane = tid & 63;
  const int wid = tid >> 6;
  const int lr = lane & 15, lg = lane >> 4;
  const int head = blockIdx.y;            // n*16 + h
  const int n = head >> 4, h = head & 15;
  const u16* qh  = Qd + head * (SEQ_L * DHEAD);
  const u16* kh  = Kd + head * (SEQ_L * DHEAD);
  const u16* vth = Vt + (size_t)head * (DHEAD * SEQ_L);
  const int q0 = blockIdx.x * 64 + wid * 16;
  short8 aq[2];
#pragma unroll
  for (int ks = 0; ks < 2; ++ks)
    aq[ks] = *(const short8*)&qh[(q0 + lr)*DHEAD + ks*32 + lg*8];
  f32x4 acc[4] = {};
  float mrun[4], lrun[4];
#pragma unroll
  for (int r = 0; r < 4; ++r){ mrun[r] = -1e30f; lrun[r] = 0.0f; }
  u16* myP = &PL[wid * 16 * 72];
  const int srow = tid >> 3, sc8 = (tid & 7) * 8;   // staging coords

  for (int kb0 = 0; kb0 < SEQ_L; kb0 += 64){
    __syncthreads();
    // stage K [64 keys][64 d] and V^T [64 d][64 keys]; 2 rows each per thread
    *(short8*)&KL[srow*72 + sc8]        = *(const short8*)&kh[(kb0 + srow)*DHEAD + sc8];
    *(short8*)&KL[(srow+32)*72 + sc8]   = *(const short8*)&kh[(kb0 + srow + 32)*DHEAD + sc8];
    *(short8*)&VtL[srow*72 + sc8]       = *(const short8*)&vth[(size_t)srow*SEQ_L + kb0 + sc8];
    *(short8*)&VtL[(srow+32)*72 + sc8]  = *(const short8*)&vth[(size_t)(srow+32)*SEQ_L + kb0 + sc8];
    __syncthreads();
    // S = Q K^T for 64 keys (scale pre-folded into Q). Lane holds S[q=lg*4+r][key=kb*16+lr].
    f32x4 s[4];
#pragma unroll
    for (int kb = 0; kb < 4; ++kb){
      short8 b0 = *(short8*)&KL[(kb*16 + lr)*72 + lg*8];
      short8 b1 = *(short8*)&KL[(kb*16 + lr)*72 + 32 + lg*8];
      f32x4 z = {0.f, 0.f, 0.f, 0.f};
      z = __builtin_amdgcn_mfma_f32_16x16x32_bf16(aq[0], b0, z, 0, 0, 0);
      z = __builtin_amdgcn_mfma_f32_16x16x32_bf16(aq[1], b1, z, 0, 0, 0);
      s[kb] = z;
    }
    // online softmax per q-row (row = lg*4 + r); reduce across the 16 lr lanes
    float alpha[4];
#pragma unroll
    for (int r = 0; r < 4; ++r){
      float mx = fmaxf(fmaxf(s[0][r], s[1][r]), fmaxf(s[2][r], s[3][r]));
#pragma unroll
      for (int mm = 1; mm < 16; mm <<= 1) mx = fmaxf(mx, __shfl_xor(mx, mm));
      const float mnew = fmaxf(mrun[r], mx);
      alpha[r] = __expf(mrun[r] - mnew);
      float ps = 0.f;
#pragma unroll
      for (int kb = 0; kb < 4; ++kb){
        const float p = __expf(s[kb][r] - mnew);
        s[kb][r] = p; ps += p;
      }
#pragma unroll
      for (int mm = 1; mm < 16; mm <<= 1) ps += __shfl_xor(ps, mm);
      lrun[r] = lrun[r]*alpha[r] + ps;
      mrun[r] = mnew;
    }
#pragma unroll
    for (int db = 0; db < 4; ++db)
#pragma unroll
      for (int r = 0; r < 4; ++r) acc[db][r] *= alpha[r];
    // P -> per-wave LDS (bf16) with XOR swizzle: col' = col ^ ((row>>2)<<4)
#pragma unroll
    for (int kb = 0; kb < 4; ++kb)
#pragma unroll
      for (int r = 0; r < 4; ++r)
        myP[(lg*4 + r)*72 + (((kb ^ lg)*16) + lr)] = f2bf(s[kb][r]);
    asm volatile("s_waitcnt lgkmcnt(0)" ::: "memory");  // cross-lane LDS RAW within wave
    __builtin_amdgcn_sched_barrier(0);
    // PV: two 32-key chunks
#pragma unroll
    for (int c = 0; c < 2; ++c){
      short8 ap = *(short8*)&myP[lr*72 + ((c*32 + lg*8) ^ ((lr >> 2) << 4))];
#pragma unroll
      for (int db = 0; db < 4; ++db){
        short8 bv = *(short8*)&VtL[(db*16 + lr)*72 + c*32 + lg*8];
        acc[db] = __builtin_amdgcn_mfma_f32_16x16x32_bf16(ap, bv, acc[db], 0, 0, 0);
      }
    }
  }
  // epilogue: ctx[l, n, h*64+d] bf16, normalized by row sum
#pragma unroll
  for (int r = 0; r < 4; ++r){
    const float inv = 1.0f / lrun[r];
    const int ql = q0 + lg*4 + r;
#pragma unroll
    for (int db = 0; db < 4; ++db)
      Ctx[(ql*NBATCH + n)*EDIM + h*DHEAD + db*16 + lr] = f2bf(acc[db][r] * inv);
  }
}

// ---------------- output projection GEMM ----------------
__global__ __launch_bounds__(256) void out_gemm(const u16* __restrict__ X,
                                                const u16* __restrict__ W,
                                                float* __restrict__ O){
  __shared__ u16 XL[128*72];
  __shared__ u16 WL[128*72];
  const int tid = threadIdx.x;
  const int lane = tid & 63;
  const int wid = tid >> 6;
  const int wr = wid >> 1, wc = wid & 1;
  const int lr = lane & 15, lg = lane >> 4;
  const int bm = blockIdx.x, bn = blockIdx.y;
  f32x4 acc[4][4] = {};
  for (int kt = 0; kt < 16; ++kt){
    __syncthreads();
#pragma unroll
    for (int it = 0; it < 4; ++it){
      int c = tid + 256*it;
      int row = c >> 3, c8 = (c & 7) * 8;
      *(short8*)&XL[row*72 + c8] = *(const short8*)&X[(bm*128 + row)*EDIM + kt*64 + c8];
      *(short8*)&WL[row*72 + c8] = *(const short8*)&W[(bn*128 + row)*EDIM + kt*64 + c8];
    }
    __syncthreads();
#pragma unroll
    for (int ks = 0; ks < 2; ++ks){
      short8 a[4], b[4];
#pragma unroll
      for (int m = 0; m < 4; ++m)  a[m]  = *(short8*)&XL[(wr*64 + m*16  + lr)*72 + ks*32 + lg*8];
#pragma unroll
      for (int nn = 0; nn < 4; ++nn) b[nn] = *(short8*)&WL[(wc*64 + nn*16 + lr)*72 + ks*32 + lg*8];
#pragma unroll
      for (int m = 0; m < 4; ++m)
#pragma unroll
        for (int nn = 0; nn < 4; ++nn)
          acc[m][nn] = __builtin_amdgcn_mfma_f32_16x16x32_bf16(a[m], b[nn], acc[m][nn], 0, 0, 0);
    }
  }
#pragma unroll
  for (int m = 0; m < 4; ++m){
    const int i0 = bm*128 + wr*64 + m*16 + lg*4;
#pragma unroll
    for (int nn = 0; nn < 4; ++nn){
      const int f = bn*128 + wc*64 + nn*16 + lr;
#pragma unroll
      for (int r = 0; r < 4; ++r)
        O[(size_t)(i0 + r)*EDIM + f] = acc[m][nn][r];
    }
  }
}

extern "C" void kernel_launch(void* const* d_in, const int* in_sizes, int n_in,
                              void* d_out, int out_size, void* d_ws, size_t ws_size,
                              hipStream_t stream){
  const float* x    = (const float*)d_in[0];
  const float* wqkv = (const float*)d_in[1];
  const float* wout = (const float*)d_in[2];
  float* out = (float*)d_out;
  u16* ws = (u16*)d_ws;
  const size_t XN  = (size_t)SEQ_L * NBATCH * EDIM; // 8388608
  const size_t WQN = (size_t)3 * EDIM * EDIM;       // 3145728
  const size_t WON = (size_t)EDIM * EDIM;           // 1048576
  u16* xb    = ws;               // bf16 x  [8192][1024]
  u16* wqkvb = xb + XN;          // bf16 Wqkv [3072][1024]
  u16* woutb = wqkvb + WQN;      // bf16 Wout [1024][1024]
  u16* qd    = woutb + WON;      // [N][H][L][DH]
  u16* kd    = qd + XN;          // [N][H][L][DH]
  u16* vt    = kd + XN;          // [N][H][DH][L]  (transposed V)
  u16* ctx   = xb;               // reuse xb region after qkv_gemm consumed it

  cvt_f32_bf16<<<(int)(XN  / 1024), 256, 0, stream>>>(x,    xb,    (int)(XN  / 4));
  cvt_f32_bf16<<<(int)(WQN / 1024), 256, 0, stream>>>(wqkv, wqkvb, (int)(WQN / 4));
  cvt_f32_bf16<<<(int)(WON / 1024), 256, 0, stream>>>(wout, woutb, (int)(WON / 4));
  qkv_gemm<<<dim3(64, 24), 256, 0, stream>>>(xb, wqkvb, qd, kd, vt);
  attn    <<<dim3(32, 64), 256, 0, stream>>>(qd, kd, vt, ctx);
  out_gemm<<<dim3(64, 8),  256, 0, stream>>>(ctx, woutb, out);
}

// Round 3
// 269.114 us; speedup vs baseline: 1.8502x; 1.2725x over previous
//
#include <hip/hip_runtime.h>
#include <hip/hip_bf16.h>

#define SEQ_L 2048
#define NBATCH 4
#define EDIM 1024
#define NHEAD 16
#define DHEAD 64

typedef __attribute__((ext_vector_type(4))) float f32x4;
typedef __attribute__((ext_vector_type(8))) short short8;
typedef unsigned short u16;
typedef unsigned long long u64;

// fold DH^-0.5 and log2(e) into Q so attention works in exp2 domain
#define QSCALE (0.125f * 1.44269504088896340736f)

__device__ __forceinline__ u16 f2bf(float f){
  unsigned u = __float_as_uint(f);
  u += 0x7fffu + ((u >> 16) & 1u);   // round-to-nearest-even
  return (u16)(u >> 16);
}
__device__ __forceinline__ unsigned pack2bf(float a, float b){
  return ((unsigned)f2bf(b) << 16) | (unsigned)f2bf(a);
}
__device__ __forceinline__ u64 pack4bf(float a, float b, float c, float d){
  return ((u64)pack2bf(c, d) << 32) | (u64)pack2bf(a, b);
}
__device__ __forceinline__ float fexp2(float x){
  float r; asm("v_exp_f32 %0, %1" : "=v"(r) : "v"(x)); return r;
}

// ---------------- fp32 -> bf16 convert ----------------
__global__ __launch_bounds__(256) void cvt_f32_bf16(const float* __restrict__ src,
                                                    u16* __restrict__ dst, int n4){
  int i = blockIdx.x * 256 + threadIdx.x;
  if (i < n4){
    float4 v = reinterpret_cast<const float4*>(src)[i];
    ushort4 o;
    o.x = f2bf(v.x); o.y = f2bf(v.y); o.z = f2bf(v.z); o.w = f2bf(v.w);
    reinterpret_cast<ushort4*>(dst)[i] = o;
  }
}

// ---------------- QKV projection GEMM ----------------
// f = which*1024 + h*64 + d.  Blocks bn<16 produce Q/K (coalesced 32B-run
// stores, Q pre-scaled by QSCALE).  Blocks bn>=16 produce V: routed through an
// LDS transpose so Vt [N][H][DH][L] is written in coalesced 64B runs
// (round-2's 2B scatter cost ~30us).
__global__ __launch_bounds__(256) void qkv_gemm(const u16* __restrict__ X,
                                                const u16* __restrict__ W,
                                                u16* __restrict__ Qd,
                                                u16* __restrict__ Kd,
                                                u16* __restrict__ Vt){
  __shared__ u16 SMEM[2*128*72];           // XL | WL, reused as T[128][134] for V
  u16* XL = SMEM;
  u16* WL = SMEM + 128*72;
  const int tid = threadIdx.x;
  const int lane = tid & 63;
  const int wid = tid >> 6;
  const int wr = wid >> 1, wc = wid & 1;
  const int lr = lane & 15, lg = lane >> 4;
  const int bm = blockIdx.x, bn = blockIdx.y;
  f32x4 acc[4][4] = {};
  for (int kt = 0; kt < 16; ++kt){
    __syncthreads();
#pragma unroll
    for (int it = 0; it < 4; ++it){
      int c = tid + 256*it;
      int row = c >> 3, c8 = (c & 7) * 8;
      *(short8*)&XL[row*72 + c8] = *(const short8*)&X[(bm*128 + row)*EDIM + kt*64 + c8];
      *(short8*)&WL[row*72 + c8] = *(const short8*)&W[(bn*128 + row)*EDIM + kt*64 + c8];
    }
    __syncthreads();
#pragma unroll
    for (int ks = 0; ks < 2; ++ks){
      short8 a[4], b[4];
#pragma unroll
      for (int m = 0; m < 4; ++m)  a[m]  = *(short8*)&XL[(wr*64 + m*16  + lr)*72 + ks*32 + lg*8];
#pragma unroll
      for (int nn = 0; nn < 4; ++nn) b[nn] = *(short8*)&WL[(wc*64 + nn*16 + lr)*72 + ks*32 + lg*8];
#pragma unroll
      for (int m = 0; m < 4; ++m)
#pragma unroll
        for (int nn = 0; nn < 4; ++nn)
          acc[m][nn] = __builtin_amdgcn_mfma_f32_16x16x32_bf16(a[m], b[nn], acc[m][nn], 0, 0, 0);
    }
  }
  if (bn < 16){
    // Q / K: [N][H][L][DH], 32B runs across lr
#pragma unroll
    for (int m = 0; m < 4; ++m){
      const int i0 = bm*128 + wr*64 + m*16 + lg*4;
      const int l = i0 >> 2;                 // i0 % 4 == 0: r indexes the batch
#pragma unroll
      for (int nn = 0; nn < 4; ++nn){
        const int f = bn*128 + wc*64 + nn*16 + lr;
        const int which = f >> 10;           // 0=Q, 1=K
        const int h = (f >> 6) & 15;
        const int d = f & 63;
        u16* dst = (which == 0) ? Qd : Kd;
        const float sc = (which == 0) ? QSCALE : 1.0f;
#pragma unroll
        for (int r = 0; r < 4; ++r)
          dst[((r*NHEAD + h)*SEQ_L + l)*DHEAD + d] = f2bf(acc[m][nn][r] * sc);
      }
    }
  } else {
    // V: transpose through LDS T[f_local][i_local], stride 134 (odd word -> 2-way banks)
    __syncthreads();                         // all waves done reading XL/WL
    u16* T = SMEM;
#pragma unroll
    for (int m = 0; m < 4; ++m){
      const int il0 = wr*64 + m*16 + lg*4;
#pragma unroll
      for (int nn = 0; nn < 4; ++nn){
        const int fl = wc*64 + nn*16 + lr;
        *(unsigned*)&T[fl*134 + il0]     = pack2bf(acc[m][nn][0], acc[m][nn][1]);
        *(unsigned*)&T[fl*134 + il0 + 2] = pack2bf(acc[m][nn][2], acc[m][nn][3]);
      }
    }
    __syncthreads();
    const int fl = tid & 127, nsel = tid >> 7;
    const int fV = bn*128 + fl - 2048;       // 0..1023
    const int hh = fV >> 6, dd = fV & 63;
#pragma unroll
    for (int nn2 = 0; nn2 < 2; ++nn2){
      const int n = nsel*2 + nn2;
      u16 val[32];
#pragma unroll
      for (int ll = 0; ll < 32; ++ll)
        val[ll] = T[fl*134 + ll*4 + n];
      const size_t base = ((size_t)(n*NHEAD + hh)*DHEAD + dd)*SEQ_L + (size_t)bm*32;
#pragma unroll
      for (int j = 0; j < 4; ++j)
        *(short8*)&Vt[base + j*8] = *(short8*)&val[j*8];
    }
  }
}

// ---------------- flash attention per (n,h) ----------------
// Swapped QK^T: S-mfma is mfma(K_frag, Q_frag) so each lane holds 16 scores
// (keys 16kb+4lg+r) of ONE q-row (q=lr).  Softmax reduce = in-lane tree +
// shfl_xor(16,32).  Scores are in exp2 domain (log2e folded into Q).
// T13 defer-max: rescale only when tile max exceeds running max by >8.
__global__ __launch_bounds__(256) void attn(const u16* __restrict__ Qd,
                                            const u16* __restrict__ Kd,
                                            const u16* __restrict__ Vt,
                                            u16* __restrict__ Ctx){
  __shared__ u16 KL[64*72];
  __shared__ u16 VtL[64*72];
  __shared__ u16 PL[4*16*72];
  const int tid = threadIdx.x;
  const int lane = tid & 63;
  const int wid = tid >> 6;
  const int lr = lane & 15, lg = lane >> 4;
  const int head = blockIdx.y;            // n*16 + h
  const int n = head >> 4, h = head & 15;
  const u16* qh  = Qd + head * (SEQ_L * DHEAD);
  const u16* kh  = Kd + head * (SEQ_L * DHEAD);
  const u16* vth = Vt + (size_t)head * (DHEAD * SEQ_L);
  const int q0 = blockIdx.x * 64 + wid * 16;
  short8 bq[2];
#pragma unroll
  for (int ks = 0; ks < 2; ++ks)
    bq[ks] = *(const short8*)&qh[(q0 + lr)*DHEAD + ks*32 + lg*8];
  f32x4 acc[4] = {};
  float mrun = -1e30f, lrun = 0.0f;       // per-lane: q = lr
  u16* myP = &PL[wid * 16 * 72];
  const int srow = tid >> 3, sc8 = (tid & 7) * 8;

  for (int kb0 = 0; kb0 < SEQ_L; kb0 += 64){
    __syncthreads();
    *(short8*)&KL[srow*72 + sc8]        = *(const short8*)&kh[(kb0 + srow)*DHEAD + sc8];
    *(short8*)&KL[(srow+32)*72 + sc8]   = *(const short8*)&kh[(kb0 + srow + 32)*DHEAD + sc8];
    *(short8*)&VtL[srow*72 + sc8]       = *(const short8*)&vth[(size_t)srow*SEQ_L + kb0 + sc8];
    *(short8*)&VtL[(srow+32)*72 + sc8]  = *(const short8*)&vth[(size_t)(srow+32)*SEQ_L + kb0 + sc8];
    __syncthreads();
    // S^T: s[kb][r] = S[key = kb*16 + lg*4 + r][q = lr]
    f32x4 s[4];
#pragma unroll
    for (int kb = 0; kb < 4; ++kb){
      short8 a0 = *(short8*)&KL[(kb*16 + lr)*72 + lg*8];
      short8 a1 = *(short8*)&KL[(kb*16 + lr)*72 + 32 + lg*8];
      f32x4 z = {0.f, 0.f, 0.f, 0.f};
      z = __builtin_amdgcn_mfma_f32_16x16x32_bf16(a0, bq[0], z, 0, 0, 0);
      z = __builtin_amdgcn_mfma_f32_16x16x32_bf16(a1, bq[1], z, 0, 0, 0);
      s[kb] = z;
    }
    // tile max for this q: in-lane tree over 16 + cross the 4 lane-groups
    float c0 = fmaxf(fmaxf(s[0][0], s[0][1]), fmaxf(s[0][2], s[0][3]));
    float c1 = fmaxf(fmaxf(s[1][0], s[1][1]), fmaxf(s[1][2], s[1][3]));
    float c2 = fmaxf(fmaxf(s[2][0], s[2][1]), fmaxf(s[2][2], s[2][3]));
    float c3 = fmaxf(fmaxf(s[3][0], s[3][1]), fmaxf(s[3][2], s[3][3]));
    float tmax = fmaxf(fmaxf(c0, c1), fmaxf(c2, c3));
    tmax = fmaxf(tmax, __shfl_xor(tmax, 16));
    tmax = fmaxf(tmax, __shfl_xor(tmax, 32));
    if (!__all(tmax <= mrun + 8.0f)){      // wave-uniform rescale (rare)
      const float mnew = fmaxf(mrun, tmax);
      const float alpha = fexp2(mrun - mnew);
      lrun *= alpha;
      mrun = mnew;
      float ar[4];
#pragma unroll
      for (int r = 0; r < 4; ++r) ar[r] = __shfl(alpha, lg*4 + r);
#pragma unroll
      for (int db = 0; db < 4; ++db)
#pragma unroll
        for (int r = 0; r < 4; ++r) acc[db][r] *= ar[r];
    }
    // P = exp2(s - mrun); pack 4 bf16 -> one b64 LDS write per kb
    float ps = 0.0f;
#pragma unroll
    for (int kb = 0; kb < 4; ++kb){
      const float p0 = fexp2(s[kb][0] - mrun);
      const float p1 = fexp2(s[kb][1] - mrun);
      const float p2 = fexp2(s[kb][2] - mrun);
      const float p3 = fexp2(s[kb][3] - mrun);
      *(u64*)&myP[lr*72 + kb*16 + lg*4] = pack4bf(p0, p1, p2, p3);
      ps += (p0 + p1) + (p2 + p3);
    }
    ps += __shfl_xor(ps, 16);
    ps += __shfl_xor(ps, 32);
    lrun += ps;
    asm volatile("s_waitcnt lgkmcnt(0)" ::: "memory");
    __builtin_amdgcn_sched_barrier(0);
    // PV: acc[db][r] = ctx[q = q0+lg*4+r][d = db*16+lr]
#pragma unroll
    for (int c = 0; c < 2; ++c){
      short8 ap = *(short8*)&myP[lr*72 + c*32 + lg*8];
#pragma unroll
      for (int db = 0; db < 4; ++db){
        short8 bv = *(short8*)&VtL[(db*16 + lr)*72 + c*32 + lg*8];
        acc[db] = __builtin_amdgcn_mfma_f32_16x16x32_bf16(ap, bv, acc[db], 0, 0, 0);
      }
    }
  }
  // epilogue: fetch denominator of q = lg*4+r from lane holding it
#pragma unroll
  for (int r = 0; r < 4; ++r){
    const float ld = __shfl(lrun, lg*4 + r);
    const float inv = 1.0f / ld;
    const int ql = q0 + lg*4 + r;
#pragma unroll
    for (int db = 0; db < 4; ++db)
      Ctx[(ql*NBATCH + n)*EDIM + h*DHEAD + db*16 + lr] = f2bf(acc[db][r] * inv);
  }
}

// ---------------- output projection GEMM ----------------
__global__ __launch_bounds__(256) void out_gemm(const u16* __restrict__ X,
                                                const u16* __restrict__ W,
                                                float* __restrict__ O){
  __shared__ u16 XL[128*72];
  __shared__ u16 WL[128*72];
  const int tid = threadIdx.x;
  const int lane = tid & 63;
  const int wid = tid >> 6;
  const int wr = wid >> 1, wc = wid & 1;
  const int lr = lane & 15, lg = lane >> 4;
  const int bm = blockIdx.x, bn = blockIdx.y;
  f32x4 acc[4][4] = {};
  for (int kt = 0; kt < 16; ++kt){
    __syncthreads();
#pragma unroll
    for (int it = 0; it < 4; ++it){
      int c = tid + 256*it;
      int row = c >> 3, c8 = (c & 7) * 8;
      *(short8*)&XL[row*72 + c8] = *(const short8*)&X[(bm*128 + row)*EDIM + kt*64 + c8];
      *(short8*)&WL[row*72 + c8] = *(const short8*)&W[(bn*128 + row)*EDIM + kt*64 + c8];
    }
    __syncthreads();
#pragma unroll
    for (int ks = 0; ks < 2; ++ks){
      short8 a[4], b[4];
#pragma unroll
      for (int m = 0; m < 4; ++m)  a[m]  = *(short8*)&XL[(wr*64 + m*16  + lr)*72 + ks*32 + lg*8];
#pragma unroll
      for (int nn = 0; nn < 4; ++nn) b[nn] = *(short8*)&WL[(wc*64 + nn*16 + lr)*72 + ks*32 + lg*8];
#pragma unroll
      for (int m = 0; m < 4; ++m)
#pragma unroll
        for (int nn = 0; nn < 4; ++nn)
          acc[m][nn] = __builtin_amdgcn_mfma_f32_16x16x32_bf16(a[m], b[nn], acc[m][nn], 0, 0, 0);
    }
  }
#pragma unroll
  for (int m = 0; m < 4; ++m){
    const int i0 = bm*128 + wr*64 + m*16 + lg*4;
#pragma unroll
    for (int nn = 0; nn < 4; ++nn){
      const int f = bn*128 + wc*64 + nn*16 + lr;
#pragma unroll
      for (int r = 0; r < 4; ++r)
        O[(size_t)(i0 + r)*EDIM + f] = acc[m][nn][r];
    }
  }
}

extern "C" void kernel_launch(void* const* d_in, const int* in_sizes, int n_in,
                              void* d_out, int out_size, void* d_ws, size_t ws_size,
                              hipStream_t stream){
  const float* x    = (const float*)d_in[0];
  const float* wqkv = (const float*)d_in[1];
  const float* wout = (const float*)d_in[2];
  float* out = (float*)d_out;
  u16* ws = (u16*)d_ws;
  const size_t XN  = (size_t)SEQ_L * NBATCH * EDIM; // 8388608
  const size_t WQN = (size_t)3 * EDIM * EDIM;       // 3145728
  const size_t WON = (size_t)EDIM * EDIM;           // 1048576
  u16* xb    = ws;               // bf16 x  [8192][1024]
  u16* wqkvb = xb + XN;          // bf16 Wqkv [3072][1024]
  u16* woutb = wqkvb + WQN;      // bf16 Wout [1024][1024]
  u16* qd    = woutb + WON;      // [N][H][L][DH]  (scaled by QSCALE)
  u16* kd    = qd + XN;          // [N][H][L][DH]
  u16* vt    = kd + XN;          // [N][H][DH][L]  (transposed V)
  u16* ctx   = xb;               // reuse xb after qkv_gemm consumed it
  // total ws use: 37,748,736 u16 = 75.5 MB (same as round 2)

  cvt_f32_bf16<<<(int)(XN  / 1024), 256, 0, stream>>>(x,    xb,    (int)(XN  / 4));
  cvt_f32_bf16<<<(int)(WQN / 1024), 256, 0, stream>>>(wqkv, wqkvb, (int)(WQN / 4));
  cvt_f32_bf16<<<(int)(WON / 1024), 256, 0, stream>>>(wout, woutb, (int)(WON / 4));
  qkv_gemm<<<dim3(64, 24), 256, 0, stream>>>(xb, wqkvb, qd, kd, vt);
  attn    <<<dim3(32, 64), 256, 0, stream>>>(qd, kd, vt, ctx);
  out_gemm<<<dim3(64, 8),  256, 0, stream>>>(ctx, woutb, out);
}

// Round 4
// 245.005 us; speedup vs baseline: 2.0323x; 1.0984x over previous
//
#include <hip/hip_runtime.h>
#include <hip/hip_bf16.h>

#define SEQ_L 2048
#define NBATCH 4
#define EDIM 1024
#define NHEAD 16
#define DHEAD 64

typedef __attribute__((ext_vector_type(4))) float f32x4;
typedef __attribute__((ext_vector_type(8))) short short8;
typedef unsigned short u16;
typedef unsigned long long u64;

// fold DH^-0.5 and log2(e) into Q so attention works in exp2 domain
#define QSCALE (0.125f * 1.44269504088896340736f)

__device__ __forceinline__ u16 f2bf(float f){
  unsigned u = __float_as_uint(f);
  u += 0x7fffu + ((u >> 16) & 1u);   // round-to-nearest-even
  return (u16)(u >> 16);
}
// hardware packed f32->bf16 (RNE): low16 = a, high16 = b  [T12 primitive]
__device__ __forceinline__ unsigned cvt_pk_bf16(float a, float b){
  unsigned r;
  asm("v_cvt_pk_bf16_f32 %0, %1, %2" : "=v"(r) : "v"(a), "v"(b));
  return r;
}
__device__ __forceinline__ float fexp2(float x){
  float r; asm("v_exp_f32 %0, %1" : "=v"(r) : "v"(x)); return r;
}

// ---------------- fp32 -> bf16 convert ----------------
__global__ __launch_bounds__(256) void cvt_f32_bf16(const float* __restrict__ src,
                                                    u16* __restrict__ dst, int n4){
  int i = blockIdx.x * 256 + threadIdx.x;
  if (i < n4){
    float4 v = reinterpret_cast<const float4*>(src)[i];
    uint2 o;
    o.x = cvt_pk_bf16(v.x, v.y);
    o.y = cvt_pk_bf16(v.z, v.w);
    *reinterpret_cast<uint2*>(dst + (size_t)i*4) = o;
  }
}

// ---------------- QKV projection GEMM ----------------
// f = which*1024 + h*64 + d.  bn<16 -> Q/K (Q pre-scaled by QSCALE).
// bn>=16 -> V via LDS transpose to Vt [N][H][DH][L] (coalesced 64B runs).
__global__ __launch_bounds__(256) void qkv_gemm(const u16* __restrict__ X,
                                                const u16* __restrict__ W,
                                                u16* __restrict__ Qd,
                                                u16* __restrict__ Kd,
                                                u16* __restrict__ Vt){
  __shared__ u16 SMEM[2*128*72];           // XL | WL, reused as T[128][134] for V
  u16* XL = SMEM;
  u16* WL = SMEM + 128*72;
  const int tid = threadIdx.x;
  const int lane = tid & 63;
  const int wid = tid >> 6;
  const int wr = wid >> 1, wc = wid & 1;
  const int lr = lane & 15, lg = lane >> 4;
  const int bm = blockIdx.x, bn = blockIdx.y;
  f32x4 acc[4][4] = {};
  for (int kt = 0; kt < 16; ++kt){
    __syncthreads();
#pragma unroll
    for (int it = 0; it < 4; ++it){
      int c = tid + 256*it;
      int row = c >> 3, c8 = (c & 7) * 8;
      *(short8*)&XL[row*72 + c8] = *(const short8*)&X[(bm*128 + row)*EDIM + kt*64 + c8];
      *(short8*)&WL[row*72 + c8] = *(const short8*)&W[(bn*128 + row)*EDIM + kt*64 + c8];
    }
    __syncthreads();
#pragma unroll
    for (int ks = 0; ks < 2; ++ks){
      short8 a[4], b[4];
#pragma unroll
      for (int m = 0; m < 4; ++m)  a[m]  = *(short8*)&XL[(wr*64 + m*16  + lr)*72 + ks*32 + lg*8];
#pragma unroll
      for (int nn = 0; nn < 4; ++nn) b[nn] = *(short8*)&WL[(wc*64 + nn*16 + lr)*72 + ks*32 + lg*8];
#pragma unroll
      for (int m = 0; m < 4; ++m)
#pragma unroll
        for (int nn = 0; nn < 4; ++nn)
          acc[m][nn] = __builtin_amdgcn_mfma_f32_16x16x32_bf16(a[m], b[nn], acc[m][nn], 0, 0, 0);
    }
  }
  if (bn < 16){
#pragma unroll
    for (int m = 0; m < 4; ++m){
      const int i0 = bm*128 + wr*64 + m*16 + lg*4;
      const int l = i0 >> 2;                 // i0 % 4 == 0: r indexes the batch
#pragma unroll
      for (int nn = 0; nn < 4; ++nn){
        const int f = bn*128 + wc*64 + nn*16 + lr;
        const int which = f >> 10;           // 0=Q, 1=K
        const int h = (f >> 6) & 15;
        const int d = f & 63;
        u16* dst = (which == 0) ? Qd : Kd;
        const float sc = (which == 0) ? QSCALE : 1.0f;
#pragma unroll
        for (int r = 0; r < 4; ++r)
          dst[((r*NHEAD + h)*SEQ_L + l)*DHEAD + d] = f2bf(acc[m][nn][r] * sc);
      }
    }
  } else {
    __syncthreads();                         // all waves done reading XL/WL
    u16* T = SMEM;
#pragma unroll
    for (int m = 0; m < 4; ++m){
      const int il0 = wr*64 + m*16 + lg*4;
#pragma unroll
      for (int nn = 0; nn < 4; ++nn){
        const int fl = wc*64 + nn*16 + lr;
        *(unsigned*)&T[fl*134 + il0]     = cvt_pk_bf16(acc[m][nn][0], acc[m][nn][1]);
        *(unsigned*)&T[fl*134 + il0 + 2] = cvt_pk_bf16(acc[m][nn][2], acc[m][nn][3]);
      }
    }
    __syncthreads();
    const int fl = tid & 127, nsel = tid >> 7;
    const int fV = bn*128 + fl - 2048;       // 0..1023
    const int hh = fV >> 6, dd = fV & 63;
#pragma unroll
    for (int nn2 = 0; nn2 < 2; ++nn2){
      const int n = nsel*2 + nn2;
      u16 val[32];
#pragma unroll
      for (int ll = 0; ll < 32; ++ll)
        val[ll] = T[fl*134 + ll*4 + n];
      const size_t base = ((size_t)(n*NHEAD + hh)*DHEAD + dd)*SEQ_L + (size_t)bm*32;
#pragma unroll
      for (int j = 0; j < 4; ++j)
        *(short8*)&Vt[base + j*8] = *(short8*)&val[j*8];
    }
  }
}

// ---------------- flash attention per (n,h) ----------------
// Swapped QK^T (lane holds scores of ONE q-row), exp2 domain, defer-max (T13),
// KVBLK=128, T14 async-STAGE: next tile's K/V global loads issue right after
// the barrier so HBM latency hides under QK/softmax/PV.
__global__ __launch_bounds__(256) void attn(const u16* __restrict__ Qd,
                                            const u16* __restrict__ Kd,
                                            const u16* __restrict__ Vt,
                                            u16* __restrict__ Ctx){
  __shared__ u16 KL[128*72];     // [128 keys][64 d]   stride 72
  __shared__ u16 VtL[64*136];    // [64 d][128 keys]   stride 136
  __shared__ u16 PL[4*16*136];   // per-wave P [16 q][128 keys] stride 136
  const int tid = threadIdx.x;
  const int lane = tid & 63;
  const int wid = tid >> 6;
  const int lr = lane & 15, lg = lane >> 4;
  const int head = blockIdx.y;            // n*16 + h
  const int n = head >> 4, h = head & 15;
  const u16* qh  = Qd + head * (SEQ_L * DHEAD);
  const u16* kh  = Kd + head * (SEQ_L * DHEAD);
  const u16* vth = Vt + (size_t)head * (DHEAD * SEQ_L);
  const int q0 = blockIdx.x * 64 + wid * 16;
  short8 bq[2];
#pragma unroll
  for (int ks = 0; ks < 2; ++ks)
    bq[ks] = *(const short8*)&qh[(q0 + lr)*DHEAD + ks*32 + lg*8];
  f32x4 acc[4] = {};
  float mrun = -1e30f, lrun = 0.0f;       // per-lane: q = lr
  u16* myP = &PL[wid * 16 * 136];
  // staging coords
  const int kr = tid >> 3, kc8 = (tid & 7) * 8;      // K: 32 rows/pass, 8 cols
  const int vr = tid >> 4, vc8 = (tid & 15) * 8;     // V: 16 rows/pass, 16 cols
  short8 kreg[4], vreg[4];
#pragma unroll
  for (int j = 0; j < 4; ++j){                       // prologue: load tile 0
    kreg[j] = *(const short8*)&kh[(j*32 + kr)*DHEAD + kc8];
    vreg[j] = *(const short8*)&vth[(size_t)(j*16 + vr)*SEQ_L + vc8];
  }

  for (int t = 0; t < SEQ_L/128; ++t){
    const int kb0 = t*128;
    __syncthreads();                                 // prev tile readers done
#pragma unroll
    for (int j = 0; j < 4; ++j){
      *(short8*)&KL[(j*32 + kr)*72 + kc8]   = kreg[j];
      *(short8*)&VtL[(j*16 + vr)*136 + vc8] = vreg[j];
    }
    __syncthreads();                                 // LDS ready
    if (t < SEQ_L/128 - 1){                          // T14: issue next-tile loads
      const int kn = kb0 + 128;
#pragma unroll
      for (int j = 0; j < 4; ++j){
        kreg[j] = *(const short8*)&kh[(kn + j*32 + kr)*DHEAD + kc8];
        vreg[j] = *(const short8*)&vth[(size_t)(j*16 + vr)*SEQ_L + kn + vc8];
      }
    }
    // S^T: s[kb][r] = S[key = kb*16 + lg*4 + r][q = lr], exp2 domain
    f32x4 s[8];
#pragma unroll
    for (int kb = 0; kb < 8; ++kb){
      short8 a0 = *(short8*)&KL[(kb*16 + lr)*72 + lg*8];
      short8 a1 = *(short8*)&KL[(kb*16 + lr)*72 + 32 + lg*8];
      f32x4 z = {0.f, 0.f, 0.f, 0.f};
      z = __builtin_amdgcn_mfma_f32_16x16x32_bf16(a0, bq[0], z, 0, 0, 0);
      z = __builtin_amdgcn_mfma_f32_16x16x32_bf16(a1, bq[1], z, 0, 0, 0);
      s[kb] = z;
    }
    // tile max: in-lane tree over 32 + cross the 4 lane-groups
    float tmax = -1e30f;
#pragma unroll
    for (int kb = 0; kb < 8; ++kb)
      tmax = fmaxf(tmax, fmaxf(fmaxf(s[kb][0], s[kb][1]), fmaxf(s[kb][2], s[kb][3])));
    tmax = fmaxf(tmax, __shfl_xor(tmax, 16));
    tmax = fmaxf(tmax, __shfl_xor(tmax, 32));
    if (!__all(tmax <= mrun + 8.0f)){      // T13 defer-max (rare rescale)
      const float mnew = fmaxf(mrun, tmax);
      const float alpha = fexp2(mrun - mnew);
      lrun *= alpha;
      mrun = mnew;
      float ar[4];
#pragma unroll
      for (int r = 0; r < 4; ++r) ar[r] = __shfl(alpha, lg*4 + r);
#pragma unroll
      for (int db = 0; db < 4; ++db)
#pragma unroll
        for (int r = 0; r < 4; ++r) acc[db][r] *= ar[r];
    }
    // P = exp2(s - mrun); cvt_pk pack -> one b64 LDS write per kb
    float ps = 0.0f;
#pragma unroll
    for (int kb = 0; kb < 8; ++kb){
      const float p0 = fexp2(s[kb][0] - mrun);
      const float p1 = fexp2(s[kb][1] - mrun);
      const float p2 = fexp2(s[kb][2] - mrun);
      const float p3 = fexp2(s[kb][3] - mrun);
      const unsigned lo = cvt_pk_bf16(p0, p1);
      const unsigned hi = cvt_pk_bf16(p2, p3);
      *(u64*)&myP[lr*136 + kb*16 + lg*4] = ((u64)hi << 32) | (u64)lo;
      ps += (p0 + p1) + (p2 + p3);
    }
    ps += __shfl_xor(ps, 16);
    ps += __shfl_xor(ps, 32);
    lrun += ps;
    asm volatile("s_waitcnt lgkmcnt(0)" ::: "memory");
    __builtin_amdgcn_sched_barrier(0);
    // PV: acc[db][r] = ctx[q = q0+lg*4+r][d = db*16+lr]
#pragma unroll
    for (int c = 0; c < 4; ++c){
      short8 ap = *(short8*)&myP[lr*136 + c*32 + lg*8];
#pragma unroll
      for (int db = 0; db < 4; ++db){
        short8 bv = *(short8*)&VtL[(db*16 + lr)*136 + c*32 + lg*8];
        acc[db] = __builtin_amdgcn_mfma_f32_16x16x32_bf16(ap, bv, acc[db], 0, 0, 0);
      }
    }
  }
  // epilogue: fetch denominator of q = lg*4+r from lane holding it
#pragma unroll
  for (int r = 0; r < 4; ++r){
    const float ld = __shfl(lrun, lg*4 + r);
    const float inv = 1.0f / ld;
    const int ql = q0 + lg*4 + r;
#pragma unroll
    for (int db = 0; db < 4; ++db)
      Ctx[(ql*NBATCH + n)*EDIM + h*DHEAD + db*16 + lr] = f2bf(acc[db][r] * inv);
  }
}

// ---------------- output projection GEMM ----------------
__global__ __launch_bounds__(256) void out_gemm(const u16* __restrict__ X,
                                                const u16* __restrict__ W,
                                                float* __restrict__ O){
  __shared__ u16 XL[128*72];
  __shared__ u16 WL[128*72];
  const int tid = threadIdx.x;
  const int lane = tid & 63;
  const int wid = tid >> 6;
  const int wr = wid >> 1, wc = wid & 1;
  const int lr = lane & 15, lg = lane >> 4;
  const int bm = blockIdx.x, bn = blockIdx.y;
  f32x4 acc[4][4] = {};
  for (int kt = 0; kt < 16; ++kt){
    __syncthreads();
#pragma unroll
    for (int it = 0; it < 4; ++it){
      int c = tid + 256*it;
      int row = c >> 3, c8 = (c & 7) * 8;
      *(short8*)&XL[row*72 + c8] = *(const short8*)&X[(bm*128 + row)*EDIM + kt*64 + c8];
      *(short8*)&WL[row*72 + c8] = *(const short8*)&W[(bn*128 + row)*EDIM + kt*64 + c8];
    }
    __syncthreads();
#pragma unroll
    for (int ks = 0; ks < 2; ++ks){
      short8 a[4], b[4];
#pragma unroll
      for (int m = 0; m < 4; ++m)  a[m]  = *(short8*)&XL[(wr*64 + m*16  + lr)*72 + ks*32 + lg*8];
#pragma unroll
      for (int nn = 0; nn < 4; ++nn) b[nn] = *(short8*)&WL[(wc*64 + nn*16 + lr)*72 + ks*32 + lg*8];
#pragma unroll
      for (int m = 0; m < 4; ++m)
#pragma unroll
        for (int nn = 0; nn < 4; ++nn)
          acc[m][nn] = __builtin_amdgcn_mfma_f32_16x16x32_bf16(a[m], b[nn], acc[m][nn], 0, 0, 0);
    }
  }
#pragma unroll
  for (int m = 0; m < 4; ++m){
    const int i0 = bm*128 + wr*64 + m*16 + lg*4;
#pragma unroll
    for (int nn = 0; nn < 4; ++nn){
      const int f = bn*128 + wc*64 + nn*16 + lr;
#pragma unroll
      for (int r = 0; r < 4; ++r)
        O[(size_t)(i0 + r)*EDIM + f] = acc[m][nn][r];
    }
  }
}

extern "C" void kernel_launch(void* const* d_in, const int* in_sizes, int n_in,
                              void* d_out, int out_size, void* d_ws, size_t ws_size,
                              hipStream_t stream){
  const float* x    = (const float*)d_in[0];
  const float* wqkv = (const float*)d_in[1];
  const float* wout = (const float*)d_in[2];
  float* out = (float*)d_out;
  u16* ws = (u16*)d_ws;
  const size_t XN  = (size_t)SEQ_L * NBATCH * EDIM; // 8388608
  const size_t WQN = (size_t)3 * EDIM * EDIM;       // 3145728
  const size_t WON = (size_t)EDIM * EDIM;           // 1048576
  u16* xb    = ws;               // bf16 x  [8192][1024]
  u16* wqkvb = xb + XN;          // bf16 Wqkv [3072][1024]
  u16* woutb = wqkvb + WQN;      // bf16 Wout [1024][1024]
  u16* qd    = woutb + WON;      // [N][H][L][DH]  (scaled by QSCALE)
  u16* kd    = qd + XN;          // [N][H][L][DH]
  u16* vt    = kd + XN;          // [N][H][DH][L]  (transposed V)
  u16* ctx   = xb;               // reuse xb after qkv_gemm consumed it

  cvt_f32_bf16<<<(int)(XN  / 1024), 256, 0, stream>>>(x,    xb,    (int)(XN  / 4));
  cvt_f32_bf16<<<(int)(WQN / 1024), 256, 0, stream>>>(wqkv, wqkvb, (int)(WQN / 4));
  cvt_f32_bf16<<<(int)(WON / 1024), 256, 0, stream>>>(wout, woutb, (int)(WON / 4));
  qkv_gemm<<<dim3(64, 24), 256, 0, stream>>>(xb, wqkvb, qd, kd, vt);
  attn    <<<dim3(32, 64), 256, 0, stream>>>(qd, kd, vt, ctx);
  out_gemm<<<dim3(64, 8),  256, 0, stream>>>(ctx, woutb, out);
}

// Round 5
// 235.715 us; speedup vs baseline: 2.1124x; 1.0394x over previous
//
#include <hip/hip_runtime.h>
#include <hip/hip_bf16.h>

#define SEQ_L 2048
#define NBATCH 4
#define EDIM 1024
#define NHEAD 16
#define DHEAD 64

typedef __attribute__((ext_vector_type(4))) float f32x4;
typedef __attribute__((ext_vector_type(8))) short short8;
typedef unsigned short u16;
typedef unsigned long long u64;

// fold DH^-0.5 and log2(e) into Q so attention works in exp2 domain
#define QSCALE (0.125f * 1.44269504088896340736f)

__device__ __forceinline__ u16 f2bf(float f){
  unsigned u = __float_as_uint(f);
  u += 0x7fffu + ((u >> 16) & 1u);   // round-to-nearest-even
  return (u16)(u >> 16);
}
// hardware packed f32->bf16 (RNE): low16 = a, high16 = b  [T12 primitive]
__device__ __forceinline__ unsigned cvt_pk_bf16(float a, float b){
  unsigned r;
  asm("v_cvt_pk_bf16_f32 %0, %1, %2" : "=v"(r) : "v"(a), "v"(b));
  return r;
}
__device__ __forceinline__ float fexp2(float x){
  float r; asm("v_exp_f32 %0, %1" : "=v"(r) : "v"(x)); return r;
}

// ---------------- fp32 -> bf16 convert ----------------
__global__ __launch_bounds__(256) void cvt_f32_bf16(const float* __restrict__ src,
                                                    u16* __restrict__ dst, int n4){
  int i = blockIdx.x * 256 + threadIdx.x;
  if (i < n4){
    float4 v = reinterpret_cast<const float4*>(src)[i];
    uint2 o;
    o.x = cvt_pk_bf16(v.x, v.y);
    o.y = cvt_pk_bf16(v.z, v.w);
    *reinterpret_cast<uint2*>(dst + (size_t)i*4) = o;
  }
}

// ---------------- QKV projection GEMM ----------------
// f = which*1024 + h*64 + d.  bn<16 -> Q/K (Q pre-scaled by QSCALE).
// bn>=16 -> V via LDS transpose to Vt [N][H][DH][L] (coalesced 64B runs).
__global__ __launch_bounds__(256) void qkv_gemm(const u16* __restrict__ X,
                                                const u16* __restrict__ W,
                                                u16* __restrict__ Qd,
                                                u16* __restrict__ Kd,
                                                u16* __restrict__ Vt){
  __shared__ u16 SMEM[2*128*72];           // XL | WL, reused as T[128][134] for V
  u16* XL = SMEM;
  u16* WL = SMEM + 128*72;
  const int tid = threadIdx.x;
  const int lane = tid & 63;
  const int wid = tid >> 6;
  const int wr = wid >> 1, wc = wid & 1;
  const int lr = lane & 15, lg = lane >> 4;
  const int bm = blockIdx.x, bn = blockIdx.y;
  f32x4 acc[4][4] = {};
  for (int kt = 0; kt < 16; ++kt){
    __syncthreads();
#pragma unroll
    for (int it = 0; it < 4; ++it){
      int c = tid + 256*it;
      int row = c >> 3, c8 = (c & 7) * 8;
      *(short8*)&XL[row*72 + c8] = *(const short8*)&X[(bm*128 + row)*EDIM + kt*64 + c8];
      *(short8*)&WL[row*72 + c8] = *(const short8*)&W[(bn*128 + row)*EDIM + kt*64 + c8];
    }
    __syncthreads();
#pragma unroll
    for (int ks = 0; ks < 2; ++ks){
      short8 a[4], b[4];
#pragma unroll
      for (int m = 0; m < 4; ++m)  a[m]  = *(short8*)&XL[(wr*64 + m*16  + lr)*72 + ks*32 + lg*8];
#pragma unroll
      for (int nn = 0; nn < 4; ++nn) b[nn] = *(short8*)&WL[(wc*64 + nn*16 + lr)*72 + ks*32 + lg*8];
#pragma unroll
      for (int m = 0; m < 4; ++m)
#pragma unroll
        for (int nn = 0; nn < 4; ++nn)
          acc[m][nn] = __builtin_amdgcn_mfma_f32_16x16x32_bf16(a[m], b[nn], acc[m][nn], 0, 0, 0);
    }
  }
  if (bn < 16){
#pragma unroll
    for (int m = 0; m < 4; ++m){
      const int i0 = bm*128 + wr*64 + m*16 + lg*4;
      const int l = i0 >> 2;                 // i0 % 4 == 0: r indexes the batch
#pragma unroll
      for (int nn = 0; nn < 4; ++nn){
        const int f = bn*128 + wc*64 + nn*16 + lr;
        const int which = f >> 10;           // 0=Q, 1=K
        const int h = (f >> 6) & 15;
        const int d = f & 63;
        u16* dst = (which == 0) ? Qd : Kd;
        const float sc = (which == 0) ? QSCALE : 1.0f;
#pragma unroll
        for (int r = 0; r < 4; ++r)
          dst[((r*NHEAD + h)*SEQ_L + l)*DHEAD + d] = f2bf(acc[m][nn][r] * sc);
      }
    }
  } else {
    __syncthreads();                         // all waves done reading XL/WL
    u16* T = SMEM;
#pragma unroll
    for (int m = 0; m < 4; ++m){
      const int il0 = wr*64 + m*16 + lg*4;
#pragma unroll
      for (int nn = 0; nn < 4; ++nn){
        const int fl = wc*64 + nn*16 + lr;
        *(unsigned*)&T[fl*134 + il0]     = cvt_pk_bf16(acc[m][nn][0], acc[m][nn][1]);
        *(unsigned*)&T[fl*134 + il0 + 2] = cvt_pk_bf16(acc[m][nn][2], acc[m][nn][3]);
      }
    }
    __syncthreads();
    const int fl = tid & 127, nsel = tid >> 7;
    const int fV = bn*128 + fl - 2048;       // 0..1023
    const int hh = fV >> 6, dd = fV & 63;
#pragma unroll
    for (int nn2 = 0; nn2 < 2; ++nn2){
      const int n = nsel*2 + nn2;
      u16 val[32];
#pragma unroll
      for (int ll = 0; ll < 32; ++ll)
        val[ll] = T[fl*134 + ll*4 + n];
      const size_t base = ((size_t)(n*NHEAD + hh)*DHEAD + dd)*SEQ_L + (size_t)bm*32;
#pragma unroll
      for (int j = 0; j < 4; ++j)
        *(short8*)&Vt[base + j*8] = *(short8*)&val[j*8];
    }
  }
}

// ---------------- flash attention per (n,h) ----------------
// Swapped QK^T + KEY-PERMUTED K staging: K rows are staged into LDS at
// permuted row pi(K) = (2*(K>>5) + ((K>>2)&1))*16 + ((K>>3)&3)*4 + (K&3),
// chosen so the QK^T output registers ARE the PV A-fragment after cvt_pk:
// lane(lg,lr) reg (kb,r) holds key (kb>>1)*32 + lg*8 + (kb&1)*4 + r, hence
// ap[c] = {pk[2c], pk[2c+1]} = P[q=lr][c*32+lg*8+0..7].  P never touches LDS.
// exp2 domain, defer-max (T13), KVBLK=128, T14 async-STAGE prefetch.
__global__ __launch_bounds__(256) void attn(const u16* __restrict__ Qd,
                                            const u16* __restrict__ Kd,
                                            const u16* __restrict__ Vt,
                                            u16* __restrict__ Ctx){
  __shared__ u16 KL[128*72];     // [128 keys, row-permuted][64 d]  stride 72
  __shared__ u16 VtL[64*136];    // [64 d][128 keys]                stride 136
  const int tid = threadIdx.x;
  const int lane = tid & 63;
  const int wid = tid >> 6;
  const int lr = lane & 15, lg = lane >> 4;
  const int head = blockIdx.y;            // n*16 + h
  const int n = head >> 4, h = head & 15;
  const u16* qh  = Qd + head * (SEQ_L * DHEAD);
  const u16* kh  = Kd + head * (SEQ_L * DHEAD);
  const u16* vth = Vt + (size_t)head * (DHEAD * SEQ_L);
  const int q0 = blockIdx.x * 64 + wid * 16;
  short8 bq[2];
#pragma unroll
  for (int ks = 0; ks < 2; ++ks)
    bq[ks] = *(const short8*)&qh[(q0 + lr)*DHEAD + ks*32 + lg*8];
  f32x4 acc[4] = {};
  float mrun = -1e30f, lrun = 0.0f;       // per-lane: q = lr
  // staging coords
  const int kr = tid >> 3, kc8 = (tid & 7) * 8;      // K: keys j*32+kr, 8 col-slices
  const int vr = tid >> 4, vc8 = (tid & 15) * 8;     // V: 16 rows/pass, 16 col-slices
  int prow[4];
#pragma unroll
  for (int j = 0; j < 4; ++j){
    const int K = j*32 + kr;
    prow[j] = ((K >> 5)*2 + ((K >> 2) & 1))*16 + ((K >> 3) & 3)*4 + (K & 3);
  }
  short8 kreg[4], vreg[4];
#pragma unroll
  for (int j = 0; j < 4; ++j){                       // prologue: load tile 0
    kreg[j] = *(const short8*)&kh[(j*32 + kr)*DHEAD + kc8];
    vreg[j] = *(const short8*)&vth[(size_t)(j*16 + vr)*SEQ_L + vc8];
  }

  for (int t = 0; t < SEQ_L/128; ++t){
    __syncthreads();                                 // prev tile readers done
#pragma unroll
    for (int j = 0; j < 4; ++j){
      *(short8*)&KL[prow[j]*72 + kc8]       = kreg[j];
      *(short8*)&VtL[(j*16 + vr)*136 + vc8] = vreg[j];
    }
    __syncthreads();                                 // LDS ready
    if (t < SEQ_L/128 - 1){                          // T14: issue next-tile loads
      const int kn = (t + 1) * 128;
#pragma unroll
      for (int j = 0; j < 4; ++j){
        kreg[j] = *(const short8*)&kh[(kn + j*32 + kr)*DHEAD + kc8];
        vreg[j] = *(const short8*)&vth[(size_t)(j*16 + vr)*SEQ_L + kn + vc8];
      }
    }
    // S^T: s[kb][r] = score(key = pi^-1(kb*16+lg*4+r), q = lr), exp2 domain
    f32x4 s[8];
#pragma unroll
    for (int kb = 0; kb < 8; ++kb){
      short8 a0 = *(short8*)&KL[(kb*16 + lr)*72 + lg*8];
      short8 a1 = *(short8*)&KL[(kb*16 + lr)*72 + 32 + lg*8];
      f32x4 z = {0.f, 0.f, 0.f, 0.f};
      z = __builtin_amdgcn_mfma_f32_16x16x32_bf16(a0, bq[0], z, 0, 0, 0);
      z = __builtin_amdgcn_mfma_f32_16x16x32_bf16(a1, bq[1], z, 0, 0, 0);
      s[kb] = z;
    }
    // tile max (key order irrelevant): in-lane tree + cross lane-groups
    float tmax = -1e30f;
#pragma unroll
    for (int kb = 0; kb < 8; ++kb)
      tmax = fmaxf(tmax, fmaxf(fmaxf(s[kb][0], s[kb][1]), fmaxf(s[kb][2], s[kb][3])));
    tmax = fmaxf(tmax, __shfl_xor(tmax, 16));
    tmax = fmaxf(tmax, __shfl_xor(tmax, 32));
    if (!__all(tmax <= mrun + 8.0f)){      // T13 defer-max (rare rescale)
      const float mnew = fmaxf(mrun, tmax);
      const float alpha = fexp2(mrun - mnew);
      lrun *= alpha;
      mrun = mnew;
      float ar[4];
#pragma unroll
      for (int r = 0; r < 4; ++r) ar[r] = __shfl(alpha, lg*4 + r);
#pragma unroll
      for (int db = 0; db < 4; ++db)
#pragma unroll
        for (int r = 0; r < 4; ++r) acc[db][r] *= ar[r];
    }
    // P = exp2(s - mrun), packed in-register -> PV A-fragments directly
    u64 pk[8];
    float ps = 0.0f;
#pragma unroll
    for (int kb = 0; kb < 8; ++kb){
      const float p0 = fexp2(s[kb][0] - mrun);
      const float p1 = fexp2(s[kb][1] - mrun);
      const float p2 = fexp2(s[kb][2] - mrun);
      const float p3 = fexp2(s[kb][3] - mrun);
      const unsigned lo = cvt_pk_bf16(p0, p1);
      const unsigned hi = cvt_pk_bf16(p2, p3);
      pk[kb] = ((u64)hi << 32) | (u64)lo;
      ps += (p0 + p1) + (p2 + p3);
    }
    ps += __shfl_xor(ps, 16);
    ps += __shfl_xor(ps, 32);
    lrun += ps;
    // PV: ap[c] = P[q=lr][key = c*32 + lg*8 + 0..7]  (lane-local!)
#pragma unroll
    for (int c = 0; c < 4; ++c){
      union { u64 q[2]; short8 s8; } ap;
      ap.q[0] = pk[c*2];
      ap.q[1] = pk[c*2 + 1];
#pragma unroll
      for (int db = 0; db < 4; ++db){
        short8 bv = *(short8*)&VtL[(db*16 + lr)*136 + c*32 + lg*8];
        acc[db] = __builtin_amdgcn_mfma_f32_16x16x32_bf16(ap.s8, bv, acc[db], 0, 0, 0);
      }
    }
  }
  // epilogue: fetch denominator of q = lg*4+r from lane holding it
#pragma unroll
  for (int r = 0; r < 4; ++r){
    const float ld = __shfl(lrun, lg*4 + r);
    const float inv = 1.0f / ld;
    const int ql = q0 + lg*4 + r;
#pragma unroll
    for (int db = 0; db < 4; ++db)
      Ctx[(ql*NBATCH + n)*EDIM + h*DHEAD + db*16 + lr] = f2bf(acc[db][r] * inv);
  }
}

// ---------------- output projection GEMM ----------------
__global__ __launch_bounds__(256) void out_gemm(const u16* __restrict__ X,
                                                const u16* __restrict__ W,
                                                float* __restrict__ O){
  __shared__ u16 XL[128*72];
  __shared__ u16 WL[128*72];
  const int tid = threadIdx.x;
  const int lane = tid & 63;
  const int wid = tid >> 6;
  const int wr = wid >> 1, wc = wid & 1;
  const int lr = lane & 15, lg = lane >> 4;
  const int bm = blockIdx.x, bn = blockIdx.y;
  f32x4 acc[4][4] = {};
  for (int kt = 0; kt < 16; ++kt){
    __syncthreads();
#pragma unroll
    for (int it = 0; it < 4; ++it){
      int c = tid + 256*it;
      int row = c >> 3, c8 = (c & 7) * 8;
      *(short8*)&XL[row*72 + c8] = *(const short8*)&X[(bm*128 + row)*EDIM + kt*64 + c8];
      *(short8*)&WL[row*72 + c8] = *(const short8*)&W[(bn*128 + row)*EDIM + kt*64 + c8];
    }
    __syncthreads();
#pragma unroll
    for (int ks = 0; ks < 2; ++ks){
      short8 a[4], b[4];
#pragma unroll
      for (int m = 0; m < 4; ++m)  a[m]  = *(short8*)&XL[(wr*64 + m*16  + lr)*72 + ks*32 + lg*8];
#pragma unroll
      for (int nn = 0; nn < 4; ++nn) b[nn] = *(short8*)&WL[(wc*64 + nn*16 + lr)*72 + ks*32 + lg*8];
#pragma unroll
      for (int m = 0; m < 4; ++m)
#pragma unroll
        for (int nn = 0; nn < 4; ++nn)
          acc[m][nn] = __builtin_amdgcn_mfma_f32_16x16x32_bf16(a[m], b[nn], acc[m][nn], 0, 0, 0);
    }
  }
#pragma unroll
  for (int m = 0; m < 4; ++m){
    const int i0 = bm*128 + wr*64 + m*16 + lg*4;
#pragma unroll
    for (int nn = 0; nn < 4; ++nn){
      const int f = bn*128 + wc*64 + nn*16 + lr;
#pragma unroll
      for (int r = 0; r < 4; ++r)
        O[(size_t)(i0 + r)*EDIM + f] = acc[m][nn][r];
    }
  }
}

extern "C" void kernel_launch(void* const* d_in, const int* in_sizes, int n_in,
                              void* d_out, int out_size, void* d_ws, size_t ws_size,
                              hipStream_t stream){
  const float* x    = (const float*)d_in[0];
  const float* wqkv = (const float*)d_in[1];
  const float* wout = (const float*)d_in[2];
  float* out = (float*)d_out;
  u16* ws = (u16*)d_ws;
  const size_t XN  = (size_t)SEQ_L * NBATCH * EDIM; // 8388608
  const size_t WQN = (size_t)3 * EDIM * EDIM;       // 3145728
  const size_t WON = (size_t)EDIM * EDIM;           // 1048576
  u16* xb    = ws;               // bf16 x  [8192][1024]
  u16* wqkvb = xb + XN;          // bf16 Wqkv [3072][1024]
  u16* woutb = wqkvb + WQN;      // bf16 Wout [1024][1024]
  u16* qd    = woutb + WON;      // [N][H][L][DH]  (scaled by QSCALE)
  u16* kd    = qd + XN;          // [N][H][L][DH]
  u16* vt    = kd + XN;          // [N][H][DH][L]  (transposed V)
  u16* ctx   = xb;               // reuse xb after qkv_gemm consumed it

  cvt_f32_bf16<<<(int)(XN  / 1024), 256, 0, stream>>>(x,    xb,    (int)(XN  / 4));
  cvt_f32_bf16<<<(int)(WQN / 1024), 256, 0, stream>>>(wqkv, wqkvb, (int)(WQN / 4));
  cvt_f32_bf16<<<(int)(WON / 1024), 256, 0, stream>>>(wout, woutb, (int)(WON / 4));
  qkv_gemm<<<dim3(64, 24), 256, 0, stream>>>(xb, wqkvb, qd, kd, vt);
  attn    <<<dim3(32, 64), 256, 0, stream>>>(qd, kd, vt, ctx);
  out_gemm<<<dim3(64, 8),  256, 0, stream>>>(ctx, woutb, out);
}

// Round 6
// 229.602 us; speedup vs baseline: 2.1686x; 1.0266x over previous
//
#include <hip/hip_runtime.h>
#include <hip/hip_bf16.h>

#define SEQ_L 2048
#define NBATCH 4
#define EDIM 1024
#define NHEAD 16
#define DHEAD 64

typedef __attribute__((ext_vector_type(4))) float f32x4;
typedef __attribute__((ext_vector_type(16))) float f32x16;
typedef __attribute__((ext_vector_type(8))) short short8;
typedef unsigned short u16;
typedef unsigned long long u64;

// fold DH^-0.5 and log2(e) into Q so attention works in exp2 domain
#define QSCALE (0.125f * 1.44269504088896340736f)

__device__ __forceinline__ u16 f2bf(float f){
  unsigned u = __float_as_uint(f);
  u += 0x7fffu + ((u >> 16) & 1u);   // round-to-nearest-even
  return (u16)(u >> 16);
}
// hardware packed f32->bf16 (RNE): low16 = a, high16 = b  [T12 primitive]
__device__ __forceinline__ unsigned cvt_pk_bf16(float a, float b){
  unsigned r;
  asm("v_cvt_pk_bf16_f32 %0, %1, %2" : "=v"(r) : "v"(a), "v"(b));
  return r;
}
__device__ __forceinline__ float fexp2(float x){
  float r; asm("v_exp_f32 %0, %1" : "=v"(r) : "v"(x)); return r;
}

// ---------------- fp32 -> bf16 convert ----------------
__global__ __launch_bounds__(256) void cvt_f32_bf16(const float* __restrict__ src,
                                                    u16* __restrict__ dst, int n4){
  int i = blockIdx.x * 256 + threadIdx.x;
  if (i < n4){
    float4 v = reinterpret_cast<const float4*>(src)[i];
    uint2 o;
    o.x = cvt_pk_bf16(v.x, v.y);
    o.y = cvt_pk_bf16(v.z, v.w);
    *reinterpret_cast<uint2*>(dst + (size_t)i*4) = o;
  }
}

// ---------------- QKV projection GEMM ----------------
// f = which*1024 + h*64 + d.  bn<16 -> Q/K (Q pre-scaled by QSCALE).
// bn>=16 -> V via LDS transpose to Vt [N][H][DH][L] (coalesced 64B runs).
__global__ __launch_bounds__(256) void qkv_gemm(const u16* __restrict__ X,
                                                const u16* __restrict__ W,
                                                u16* __restrict__ Qd,
                                                u16* __restrict__ Kd,
                                                u16* __restrict__ Vt){
  __shared__ u16 SMEM[2*128*72];           // XL | WL, reused as T[128][134] for V
  u16* XL = SMEM;
  u16* WL = SMEM + 128*72;
  const int tid = threadIdx.x;
  const int lane = tid & 63;
  const int wid = tid >> 6;
  const int wr = wid >> 1, wc = wid & 1;
  const int lr = lane & 15, lg = lane >> 4;
  const int bm = blockIdx.x, bn = blockIdx.y;
  f32x4 acc[4][4] = {};
  for (int kt = 0; kt < 16; ++kt){
    __syncthreads();
#pragma unroll
    for (int it = 0; it < 4; ++it){
      int c = tid + 256*it;
      int row = c >> 3, c8 = (c & 7) * 8;
      *(short8*)&XL[row*72 + c8] = *(const short8*)&X[(bm*128 + row)*EDIM + kt*64 + c8];
      *(short8*)&WL[row*72 + c8] = *(const short8*)&W[(bn*128 + row)*EDIM + kt*64 + c8];
    }
    __syncthreads();
#pragma unroll
    for (int ks = 0; ks < 2; ++ks){
      short8 a[4], b[4];
#pragma unroll
      for (int m = 0; m < 4; ++m)  a[m]  = *(short8*)&XL[(wr*64 + m*16  + lr)*72 + ks*32 + lg*8];
#pragma unroll
      for (int nn = 0; nn < 4; ++nn) b[nn] = *(short8*)&WL[(wc*64 + nn*16 + lr)*72 + ks*32 + lg*8];
#pragma unroll
      for (int m = 0; m < 4; ++m)
#pragma unroll
        for (int nn = 0; nn < 4; ++nn)
          acc[m][nn] = __builtin_amdgcn_mfma_f32_16x16x32_bf16(a[m], b[nn], acc[m][nn], 0, 0, 0);
    }
  }
  if (bn < 16){
#pragma unroll
    for (int m = 0; m < 4; ++m){
      const int i0 = bm*128 + wr*64 + m*16 + lg*4;
      const int l = i0 >> 2;                 // i0 % 4 == 0: r indexes the batch
#pragma unroll
      for (int nn = 0; nn < 4; ++nn){
        const int f = bn*128 + wc*64 + nn*16 + lr;
        const int which = f >> 10;           // 0=Q, 1=K
        const int h = (f >> 6) & 15;
        const int d = f & 63;
        u16* dst = (which == 0) ? Qd : Kd;
        const float sc = (which == 0) ? QSCALE : 1.0f;
#pragma unroll
        for (int r = 0; r < 4; ++r)
          dst[((r*NHEAD + h)*SEQ_L + l)*DHEAD + d] = f2bf(acc[m][nn][r] * sc);
      }
    }
  } else {
    __syncthreads();                         // all waves done reading XL/WL
    u16* T = SMEM;
#pragma unroll
    for (int m = 0; m < 4; ++m){
      const int il0 = wr*64 + m*16 + lg*4;
#pragma unroll
      for (int nn = 0; nn < 4; ++nn){
        const int fl = wc*64 + nn*16 + lr;
        *(unsigned*)&T[fl*134 + il0]     = cvt_pk_bf16(acc[m][nn][0], acc[m][nn][1]);
        *(unsigned*)&T[fl*134 + il0 + 2] = cvt_pk_bf16(acc[m][nn][2], acc[m][nn][3]);
      }
    }
    __syncthreads();
    const int fl = tid & 127, nsel = tid >> 7;
    const int fV = bn*128 + fl - 2048;       // 0..1023
    const int hh = fV >> 6, dd = fV & 63;
#pragma unroll
    for (int nn2 = 0; nn2 < 2; ++nn2){
      const int n = nsel*2 + nn2;
      u16 val[32];
#pragma unroll
      for (int ll = 0; ll < 32; ++ll)
        val[ll] = T[fl*134 + ll*4 + n];
      const size_t base = ((size_t)(n*NHEAD + hh)*DHEAD + dd)*SEQ_L + (size_t)bm*32;
#pragma unroll
      for (int j = 0; j < 4; ++j)
        *(short8*)&Vt[base + j*8] = *(short8*)&val[j*8];
    }
  }
}

// ---------------- flash attention per (n,h) ----------------
// 32x32x16 MFMA core.  Block = 4 waves x 32 q-rows = 128 q; KVBLK = 64.
// Swapped QK^T: D = Kstaged x Q -> lane holds q = lane&31, 16 key-rows/reg.
// K rows staged with pi = swap(bit2,bit3) so PV A-frag for k-step s is
// exactly D regs [8s..8s+7]: actual key of reg r=8s+j at half hf is
// j + 8*hf + 16*s (+32c).  P stays in registers (cvt_pk pairs).
// K/V each read from LDS exactly once per wave: 16 b128 reads + 4 staging
// writes per wave-tile (vs 40 in the 16x16 version) -> DS pipe unbound.
// Stride 66 u16 => every LDS pattern <=2-way bank alias (free).
__global__ __launch_bounds__(256) void attn(const u16* __restrict__ Qd,
                                            const u16* __restrict__ Kd,
                                            const u16* __restrict__ Vt,
                                            u16* __restrict__ Ctx){
  __shared__ u16 KL[64*66];      // [64 keys, pi-permuted rows][64 d]
  __shared__ u16 VtL[64*66];     // [64 d][64 keys]
  const int tid = threadIdx.x;
  const int lane = tid & 63;
  const int wid = tid >> 6;
  const int l31 = lane & 31, hf = lane >> 5;
  const int head = blockIdx.y;            // n*16 + h
  const int n = head >> 4, h = head & 15;
  const u16* qh  = Qd + head * (SEQ_L * DHEAD);
  const u16* kh  = Kd + head * (SEQ_L * DHEAD);
  const u16* vth = Vt + (size_t)head * (DHEAD * SEQ_L);
  const int q0 = blockIdx.x * 128 + wid * 32;
  // Q B-frags: bq[st] = Q[q0+l31][st*16 + hf*8 + 0..7]
  short8 bq[4];
#pragma unroll
  for (int st = 0; st < 4; ++st)
    bq[st] = *(const short8*)&qh[(q0 + l31)*DHEAD + st*16 + hf*8];
  f32x16 acc[2] = {};                     // ctx: d = db*32 + l31, q per reg
  float mrun = -1e30f, lrun = 0.0f;       // per-lane state for q = l31
  // staging coords: row = tid>>3 (0..31, +32 second pass), 8 col-slices
  const int srow = tid >> 3, sc8 = (tid & 7) * 8;
  const int prow = (srow & ~12) | ((srow & 4) << 1) | ((srow & 8) >> 1);  // swap b2,b3
  short8 kreg[2], vreg[2];
#pragma unroll
  for (int j = 0; j < 2; ++j){            // prologue: tile 0
    kreg[j] = *(const short8*)&kh[(j*32 + srow)*DHEAD + sc8];
    vreg[j] = *(const short8*)&vth[(size_t)(j*32 + srow)*SEQ_L + sc8];
  }

  for (int t = 0; t < SEQ_L/64; ++t){
    __syncthreads();                      // prev tile readers done
    *(short8*)&KL[prow*66 + sc8]       = kreg[0];
    *(short8*)&KL[(prow+32)*66 + sc8]  = kreg[1];
    *(short8*)&VtL[srow*66 + sc8]      = vreg[0];
    *(short8*)&VtL[(srow+32)*66 + sc8] = vreg[1];
    __syncthreads();                      // LDS ready
    if (t < SEQ_L/64 - 1){                // T14: prefetch next tile into regs
      const int kn = (t + 1) * 64;
#pragma unroll
      for (int j = 0; j < 2; ++j){
        kreg[j] = *(const short8*)&kh[(kn + j*32 + srow)*DHEAD + sc8];
        vreg[j] = *(const short8*)&vth[(size_t)(j*32 + srow)*SEQ_L + kn + sc8];
      }
    }
#pragma unroll
    for (int c = 0; c < 2; ++c){          // two 32-key sub-blocks
      // QK: D[staged-key][q], 4 d-steps
      f32x16 sD = {0.f,0.f,0.f,0.f,0.f,0.f,0.f,0.f,0.f,0.f,0.f,0.f,0.f,0.f,0.f,0.f};
#pragma unroll
      for (int st = 0; st < 4; ++st){
        short8 ak = *(short8*)&KL[(c*32 + l31)*66 + st*16 + hf*8];
        sD = __builtin_amdgcn_mfma_f32_32x32x16_bf16(ak, bq[st], sD, 0, 0, 0);
      }
      // block max for q = l31: in-lane tree over 16 regs + cross-half
      float tmax = sD[0];
#pragma unroll
      for (int r = 1; r < 16; ++r) tmax = fmaxf(tmax, sD[r]);
      tmax = fmaxf(tmax, __shfl_xor(tmax, 32));
      if (!__all(tmax <= mrun + 8.0f)){   // T13 defer-max (rare, wave-uniform)
        const float mnew = fmaxf(mrun, tmax);
        const float alpha = fexp2(mrun - mnew);
        lrun *= alpha;
        mrun = mnew;
#pragma unroll
        for (int r = 0; r < 16; ++r){
          const float aq = __shfl(alpha, (r&3) + 8*(r>>2) + 4*hf);
          acc[0][r] *= aq;
          acc[1][r] *= aq;
        }
      }
      // P = exp2(s - mrun); sum; pack pairs -> PV A-frags (in-register)
      float p[16];
      float ps = 0.f;
#pragma unroll
      for (int r = 0; r < 16; ++r){
        p[r] = fexp2(sD[r] - mrun);
        ps += p[r];
      }
      ps += __shfl_xor(ps, 32);
      lrun += ps;
#pragma unroll
      for (int s = 0; s < 2; ++s){
        union { unsigned u[4]; short8 s8; } pa;
#pragma unroll
        for (int jj = 0; jj < 4; ++jj)
          pa.u[jj] = cvt_pk_bf16(p[s*8 + jj*2], p[s*8 + jj*2 + 1]);
#pragma unroll
        for (int db = 0; db < 2; ++db){
          short8 bv = *(short8*)&VtL[(db*32 + l31)*66 + c*32 + s*16 + hf*8];
          acc[db] = __builtin_amdgcn_mfma_f32_32x32x16_bf16(pa.s8, bv, acc[db], 0, 0, 0);
        }
      }
    }
  }
  // epilogue: acc row r holds q-local = (r&3)+8*(r>>2)+4*hf; denom at lane q
#pragma unroll
  for (int r = 0; r < 16; ++r){
    const int ql = (r&3) + 8*(r>>2) + 4*hf;
    const float denom = __shfl(lrun, ql);
    const float inv = 1.0f / denom;
    const int q = q0 + ql;
#pragma unroll
    for (int db = 0; db < 2; ++db)
      Ctx[(q*NBATCH + n)*EDIM + h*DHEAD + db*32 + l31] = f2bf(acc[db][r] * inv);
  }
}

// ---------------- output projection GEMM ----------------
__global__ __launch_bounds__(256) void out_gemm(const u16* __restrict__ X,
                                                const u16* __restrict__ W,
                                                float* __restrict__ O){
  __shared__ u16 XL[128*72];
  __shared__ u16 WL[128*72];
  const int tid = threadIdx.x;
  const int lane = tid & 63;
  const int wid = tid >> 6;
  const int wr = wid >> 1, wc = wid & 1;
  const int lr = lane & 15, lg = lane >> 4;
  const int bm = blockIdx.x, bn = blockIdx.y;
  f32x4 acc[4][4] = {};
  for (int kt = 0; kt < 16; ++kt){
    __syncthreads();
#pragma unroll
    for (int it = 0; it < 4; ++it){
      int c = tid + 256*it;
      int row = c >> 3, c8 = (c & 7) * 8;
      *(short8*)&XL[row*72 + c8] = *(const short8*)&X[(bm*128 + row)*EDIM + kt*64 + c8];
      *(short8*)&WL[row*72 + c8] = *(const short8*)&W[(bn*128 + row)*EDIM + kt*64 + c8];
    }
    __syncthreads();
#pragma unroll
    for (int ks = 0; ks < 2; ++ks){
      short8 a[4], b[4];
#pragma unroll
      for (int m = 0; m < 4; ++m)  a[m]  = *(short8*)&XL[(wr*64 + m*16  + lr)*72 + ks*32 + lg*8];
#pragma unroll
      for (int nn = 0; nn < 4; ++nn) b[nn] = *(short8*)&WL[(wc*64 + nn*16 + lr)*72 + ks*32 + lg*8];
#pragma unroll
      for (int m = 0; m < 4; ++m)
#pragma unroll
        for (int nn = 0; nn < 4; ++nn)
          acc[m][nn] = __builtin_amdgcn_mfma_f32_16x16x32_bf16(a[m], b[nn], acc[m][nn], 0, 0, 0);
    }
  }
#pragma unroll
  for (int m = 0; m < 4; ++m){
    const int i0 = bm*128 + wr*64 + m*16 + lg*4;
#pragma unroll
    for (int nn = 0; nn < 4; ++nn){
      const int f = bn*128 + wc*64 + nn*16 + lr;
#pragma unroll
      for (int r = 0; r < 4; ++r)
        O[(size_t)(i0 + r)*EDIM + f] = acc[m][nn][r];
    }
  }
}

extern "C" void kernel_launch(void* const* d_in, const int* in_sizes, int n_in,
                              void* d_out, int out_size, void* d_ws, size_t ws_size,
                              hipStream_t stream){
  const float* x    = (const float*)d_in[0];
  const float* wqkv = (const float*)d_in[1];
  const float* wout = (const float*)d_in[2];
  float* out = (float*)d_out;
  u16* ws = (u16*)d_ws;
  const size_t XN  = (size_t)SEQ_L * NBATCH * EDIM; // 8388608
  const size_t WQN = (size_t)3 * EDIM * EDIM;       // 3145728
  const size_t WON = (size_t)EDIM * EDIM;           // 1048576
  u16* xb    = ws;               // bf16 x  [8192][1024]
  u16* wqkvb = xb + XN;          // bf16 Wqkv [3072][1024]
  u16* woutb = wqkvb + WQN;      // bf16 Wout [1024][1024]
  u16* qd    = woutb + WON;      // [N][H][L][DH]  (scaled by QSCALE)
  u16* kd    = qd + XN;          // [N][H][L][DH]
  u16* vt    = kd + XN;          // [N][H][DH][L]  (transposed V)
  u16* ctx   = xb;               // reuse xb after qkv_gemm consumed it

  cvt_f32_bf16<<<(int)(XN  / 1024), 256, 0, stream>>>(x,    xb,    (int)(XN  / 4));
  cvt_f32_bf16<<<(int)(WQN / 1024), 256, 0, stream>>>(wqkv, wqkvb, (int)(WQN / 4));
  cvt_f32_bf16<<<(int)(WON / 1024), 256, 0, stream>>>(wout, woutb, (int)(WON / 4));
  qkv_gemm<<<dim3(64, 24), 256, 0, stream>>>(xb, wqkvb, qd, kd, vt);
  attn    <<<dim3(16, 64), 256, 0, stream>>>(qd, kd, vt, ctx);
  out_gemm<<<dim3(64, 8),  256, 0, stream>>>(ctx, woutb, out);
}